// Round 4
// baseline (188.474 us; speedup 1.0000x reference)
//
#include <hip/hip_runtime.h>
#include <math.h>

// Problem constants
#define NB   256   // batch
#define NIN  1024  // in_features
#define NOUT 1024  // out_features
#define NSF  128   // sub_features (rank)
#define NQ   1024  // q_features
#define NS   64    // num subnets
#define NACT 8     // top-k active
#define NSLOT 64   // per-subnet slot capacity (nb ~ Binom(256,~1/8): max ~50)
#define NIC  8     // i-chunks in B1 (parallelism via k-split; chunk = 128)

// Workspace layout (bytes). Total ~27.3 MB.
#define WS_COUNTS 0          // 64 ints
#define WS_LISTBK 1024       // int  [64][64]
#define WS_LISTW  17408      // float[64][64]
#define WS_Y      33792      // float[2048][1024] Ybuf[b*8+k][o]          (8.39 MB)
#define WS_HSUM   8422400    // float[64][64][128] Hsum[s][slot][r]       (2.10 MB)
#define WS_H      10519552   // float[8][64][64][128] Hpart[ic][s][slot][r] (16.78 MB)

// ---------------------------------------------------------------------------
// Kernel A: att = q @ Wk^T + bk; top-8; softmax; append (b*8+k, w) to lists.
// 256 blocks (1 row each) x 256 threads (4 lanes per subnet).
// ---------------------------------------------------------------------------
__global__ __launch_bounds__(256) void attn_topk(
    const float* __restrict__ q, const float* __restrict__ Wk,
    const float* __restrict__ bk, int* __restrict__ counts,
    int* __restrict__ list_bk, float* __restrict__ list_w)
{
    int b = blockIdx.x;
    int t = threadIdx.x;

    __shared__ float qs[NQ];
    __shared__ float att[NS];

    ((float4*)qs)[t] = ((const float4*)(q + (size_t)b * NQ))[t];
    __syncthreads();

    int sid = t >> 2;   // subnet 0..63
    int il  = t & 3;
    const float* wrow = Wk + (size_t)sid * NQ + (il << 2);
    const float* qrow = qs + (il << 2);
    float acc = 0.f;
    #pragma unroll 8
    for (int i = 0; i < NQ; i += 16) {
        float4 w4 = *(const float4*)(wrow + i);
        float4 q4 = *(const float4*)(qrow + i);
        acc += w4.x * q4.x + w4.y * q4.y + w4.z * q4.z + w4.w * q4.w;
    }
    acc += __shfl_xor(acc, 1);
    acc += __shfl_xor(acc, 2);
    if (il == 0) att[sid] = acc + bk[sid];
    __syncthreads();

    if (t < 64) {   // wave 0: top-8 butterfly + softmax + append
        float v = att[t];
        float top_v[NACT]; int top_i[NACT];
        #pragma unroll
        for (int k = 0; k < NACT; ++k) {
            float mv = v; int mi = t;
            #pragma unroll
            for (int off = 1; off < 64; off <<= 1) {
                float ov = __shfl_xor(mv, off);
                int   oi = __shfl_xor(mi, off);
                if (ov > mv || (ov == mv && oi < mi)) { mv = ov; mi = oi; }
            }
            top_v[k] = mv; top_i[k] = mi;
            if (t == mi) v = -INFINITY;
        }
        if (t == 0) {
            float m = top_v[0], den = 0.f, e[NACT];
            #pragma unroll
            for (int k = 0; k < NACT; ++k) { e[k] = expf(top_v[k] - m); den += e[k]; }
            float inv = 1.f / den;
            #pragma unroll
            for (int k = 0; k < NACT; ++k) {
                int s = top_i[k];
                int slot = atomicAdd(&counts[s], 1);
                if (slot < NSLOT) {
                    list_bk[s * NSLOT + slot] = b * NACT + k;
                    list_w[s * NSLOT + slot]  = e[k] * inv;
                }
            }
        }
    }
}

// ---------------------------------------------------------------------------
// Kernel B1: Hpart[ic][s][j][r] = V0[s, r, ic*128:+128] . x[b_j, same]
// grid (64 s, 8 ic, 2 jt) -> ~740 active blocks. Tile 128r x 32j, 4x4/thread.
// Two 64-i sub-chunks with register prefetch to hide HBM latency.
// ---------------------------------------------------------------------------
__global__ __launch_bounds__(256) void subnet_h(
    const float* __restrict__ x, const float* __restrict__ V0,
    const int* __restrict__ counts, const int* __restrict__ list_bk,
    float* __restrict__ Hpart)
{
    int s  = blockIdx.x;
    int ic = blockIdx.y;          // i-chunk of 128
    int jt = blockIdx.z;
    int nb = counts[s]; if (nb > NSLOT) nb = NSLOT;
    if (jt * 32 >= nb) return;
    int t = threadIdx.x;

    __shared__ float v0t[64][129];  // [i][r], odd pad
    __shared__ float xt[64][33];    // [i][j], odd pad
    __shared__ int   bidx[32];

    if (t < 32) {
        int idx = jt * 32 + t;
        bidx[t] = (idx < nb) ? (list_bk[s * NSLOT + idx] >> 3) : 0;
    }
    __syncthreads();

    int i0 = ic * 128;
    const float* V0s = V0 + (size_t)s * NSF * NIN + i0;

    int lr  = t >> 4;            // 0..15
    int li4 = (t & 15) << 2;     // 0..60 (i within sub-chunk)
    int to4 = (t & 31) << 2;     // r-offset 0..124
    int tj4 = (t >> 5) << 2;     // j-offset 0..28

    float4 va[8], vb[2];
    float acc[4][4] = {};

    // prologue: prefetch sub-chunk 0
    #pragma unroll
    for (int rep = 0; rep < 8; ++rep)
        va[rep] = *(const float4*)(V0s + (size_t)(rep * 16 + lr) * NIN + li4);
    #pragma unroll
    for (int rep = 0; rep < 2; ++rep)
        vb[rep] = *(const float4*)(x + (size_t)bidx[rep * 16 + lr] * NIN + i0 + li4);

    for (int ks = 0; ks < 128; ks += 64) {
        #pragma unroll
        for (int rep = 0; rep < 8; ++rep) {
            int r = rep * 16 + lr;
            v0t[li4 + 0][r] = va[rep].x; v0t[li4 + 1][r] = va[rep].y;
            v0t[li4 + 2][r] = va[rep].z; v0t[li4 + 3][r] = va[rep].w;
        }
        #pragma unroll
        for (int rep = 0; rep < 2; ++rep) {
            int j = rep * 16 + lr;
            xt[li4 + 0][j] = vb[rep].x; xt[li4 + 1][j] = vb[rep].y;
            xt[li4 + 2][j] = vb[rep].z; xt[li4 + 3][j] = vb[rep].w;
        }
        __syncthreads();
        if (ks == 0) {  // prefetch sub-chunk 1
            #pragma unroll
            for (int rep = 0; rep < 8; ++rep)
                va[rep] = *(const float4*)(V0s + (size_t)(rep * 16 + lr) * NIN + 64 + li4);
            #pragma unroll
            for (int rep = 0; rep < 2; ++rep)
                vb[rep] = *(const float4*)(x + (size_t)bidx[rep * 16 + lr] * NIN + i0 + 64 + li4);
        }
        #pragma unroll 8
        for (int i = 0; i < 64; ++i) {
            float4 a = *(const float4*)&v0t[i][to4];
            float4 h = *(const float4*)&xt[i][tj4];
            acc[0][0] += a.x * h.x; acc[0][1] += a.x * h.y; acc[0][2] += a.x * h.z; acc[0][3] += a.x * h.w;
            acc[1][0] += a.y * h.x; acc[1][1] += a.y * h.y; acc[1][2] += a.y * h.z; acc[1][3] += a.y * h.w;
            acc[2][0] += a.z * h.x; acc[2][1] += a.z * h.y; acc[2][2] += a.z * h.z; acc[2][3] += a.z * h.w;
            acc[3][0] += a.w * h.x; acc[3][1] += a.w * h.y; acc[3][2] += a.w * h.z; acc[3][3] += a.w * h.w;
        }
        __syncthreads();
    }

    float* Hp = Hpart + ((size_t)(ic * NS + s) * NSLOT + jt * 32) * NSF;
    #pragma unroll
    for (int ji = 0; ji < 4; ++ji) {
        *(float4*)(Hp + (size_t)(tj4 + ji) * NSF + to4) =
            make_float4(acc[0][ji], acc[1][ji], acc[2][ji], acc[3][ji]);
    }
}

// ---------------------------------------------------------------------------
// Kernel B1.5: Hsum = sum_ic Hpart[ic]. Pure streaming float4.
// 2.1 MB out, 16.8 MB in. 512 blocks x 256 threads.
// ---------------------------------------------------------------------------
__global__ __launch_bounds__(256) void hsum_k(
    const float* __restrict__ Hpart, float* __restrict__ Hsum)
{
    int idx4 = blockIdx.x * 256 + threadIdx.x;       // 0 .. 131071
    const float4* hp = (const float4*)Hpart + idx4;
    float4 a = hp[0];
    #pragma unroll
    for (int ic = 1; ic < NIC; ++ic) {
        float4 v = hp[(size_t)ic * 131072];
        a.x += v.x; a.y += v.y; a.z += v.z; a.w += v.w;
    }
    ((float4*)Hsum)[idx4] = a;
}

// ---------------------------------------------------------------------------
// Kernel B2: Y[o,j] = V1[s,o,:] . Hsum[s,j,:]; Ybuf[bk_j][o] = w_j * Y[o,j].
// grid (64 s, 8 ot, 2 jt). Tile 128o x 32j, K=128 in two 64-r chunks with
// register prefetch. Plain stores (no atomics).
// ---------------------------------------------------------------------------
__global__ __launch_bounds__(256) void subnet_out(
    const float* __restrict__ V1, const int* __restrict__ counts,
    const int* __restrict__ list_bk, const float* __restrict__ list_w,
    const float* __restrict__ Hsum, float* __restrict__ Ybuf)
{
    int s  = blockIdx.x;
    int ot = blockIdx.y;
    int jt = blockIdx.z;
    int nb = counts[s]; if (nb > NSLOT) nb = NSLOT;
    if (jt * 32 >= nb) return;
    int t = threadIdx.x;

    __shared__ float v1t[64][129];  // [r][o]
    __shared__ float hs[64][33];    // [r][j]
    __shared__ int   bkx[32];
    __shared__ float wjs[32];

    if (t < 32) {
        int idx = jt * 32 + t;
        bool v = idx < nb;
        bkx[t] = v ? list_bk[s * NSLOT + idx] : 0;
        wjs[t] = v ? list_w[s * NSLOT + idx] : 0.f;
    }

    const float* V1s = V1 + (size_t)s * NOUT * NSF + (size_t)ot * 128 * NSF;
    const float* Hp  = Hsum + ((size_t)s * NSLOT + jt * 32) * NSF;

    int lr  = t >> 4;            // 0..15
    int r4  = (t & 15) << 2;     // r within chunk
    int to4 = (t & 31) << 2;     // o-offset 0..124
    int tj4 = (t >> 5) << 2;     // j-offset 0..28

    float4 wa[8], ha[2];
    float acc[4][4] = {};

    // prefetch chunk 0
    #pragma unroll
    for (int rep = 0; rep < 8; ++rep)
        wa[rep] = *(const float4*)(V1s + (size_t)(rep * 16 + lr) * NSF + r4);
    #pragma unroll
    for (int rep = 0; rep < 2; ++rep)
        ha[rep] = *(const float4*)(Hp + (size_t)(rep * 16 + lr) * NSF + r4);

    for (int rc = 0; rc < NSF; rc += 64) {
        #pragma unroll
        for (int rep = 0; rep < 8; ++rep) {
            int o = rep * 16 + lr;
            v1t[r4 + 0][o] = wa[rep].x; v1t[r4 + 1][o] = wa[rep].y;
            v1t[r4 + 2][o] = wa[rep].z; v1t[r4 + 3][o] = wa[rep].w;
        }
        #pragma unroll
        for (int rep = 0; rep < 2; ++rep) {
            int j = rep * 16 + lr;
            hs[r4 + 0][j] = ha[rep].x; hs[r4 + 1][j] = ha[rep].y;
            hs[r4 + 2][j] = ha[rep].z; hs[r4 + 3][j] = ha[rep].w;
        }
        __syncthreads();
        if (rc == 0) {   // prefetch chunk 1
            #pragma unroll
            for (int rep = 0; rep < 8; ++rep)
                wa[rep] = *(const float4*)(V1s + (size_t)(rep * 16 + lr) * NSF + 64 + r4);
            #pragma unroll
            for (int rep = 0; rep < 2; ++rep)
                ha[rep] = *(const float4*)(Hp + (size_t)(rep * 16 + lr) * NSF + 64 + r4);
        }
        #pragma unroll 8
        for (int r = 0; r < 64; ++r) {
            float4 a = *(const float4*)&v1t[r][to4];
            float4 h = *(const float4*)&hs[r][tj4];
            acc[0][0] += a.x * h.x; acc[0][1] += a.x * h.y; acc[0][2] += a.x * h.z; acc[0][3] += a.x * h.w;
            acc[1][0] += a.y * h.x; acc[1][1] += a.y * h.y; acc[1][2] += a.y * h.z; acc[1][3] += a.y * h.w;
            acc[2][0] += a.z * h.x; acc[2][1] += a.z * h.y; acc[2][2] += a.z * h.z; acc[2][3] += a.z * h.w;
            acc[3][0] += a.w * h.x; acc[3][1] += a.w * h.y; acc[3][2] += a.w * h.z; acc[3][3] += a.w * h.w;
        }
        __syncthreads();
    }

    #pragma unroll
    for (int ji = 0; ji < 4; ++ji) {
        int idx = jt * 32 + tj4 + ji;
        if (idx < nb) {
            int   bki = bkx[tj4 + ji];
            float w   = wjs[tj4 + ji];
            *(float4*)(Ybuf + (size_t)bki * NOUT + ot * 128 + to4) =
                make_float4(w * acc[0][ji], w * acc[1][ji], w * acc[2][ji], w * acc[3][ji]);
        }
    }
}

// ---------------------------------------------------------------------------
// Kernel C: out[b][o] = sum_k Ybuf[b*8+k][o]. 256 blocks x 256 thr, float4.
// ---------------------------------------------------------------------------
__global__ __launch_bounds__(256) void reduce_out(
    const float* __restrict__ Ybuf, float* __restrict__ out)
{
    int b = blockIdx.x, t = threadIdx.x;
    const float* yb = Ybuf + (size_t)b * NACT * NOUT + (t << 2);
    float4 a = *(const float4*)yb;
    #pragma unroll
    for (int k = 1; k < NACT; ++k) {
        float4 v = *(const float4*)(yb + (size_t)k * NOUT);
        a.x += v.x; a.y += v.y; a.z += v.z; a.w += v.w;
    }
    *(float4*)(out + (size_t)b * NOUT + (t << 2)) = a;
}

// ---------------------------------------------------------------------------
extern "C" void kernel_launch(void* const* d_in, const int* in_sizes, int n_in,
                              void* d_out, int out_size, void* d_ws, size_t ws_size,
                              hipStream_t stream)
{
    const float* x  = (const float*)d_in[0];
    const float* q  = (const float*)d_in[1];
    const float* Wk = (const float*)d_in[2];
    const float* bk = (const float*)d_in[3];
    const float* V0 = (const float*)d_in[4];
    const float* V1 = (const float*)d_in[5];
    float* out = (float*)d_out;

    char* ws = (char*)d_ws;
    int*   counts  = (int*)(ws + WS_COUNTS);
    int*   list_bk = (int*)(ws + WS_LISTBK);
    float* list_w  = (float*)(ws + WS_LISTW);
    float* Ybuf    = (float*)(ws + WS_Y);
    float* Hsum    = (float*)(ws + WS_HSUM);
    float* Hpart   = (float*)(ws + WS_H);

    hipMemsetAsync(counts, 0, 1024, stream);

    attn_topk<<<dim3(NB), 256, 0, stream>>>(q, Wk, bk, counts, list_bk, list_w);
    subnet_h<<<dim3(NS, NIC, 2), 256, 0, stream>>>(x, V0, counts, list_bk, Hpart);
    hsum_k<<<dim3(512), 256, 0, stream>>>(Hpart, Hsum);
    subnet_out<<<dim3(NS, 8, 2), 256, 0, stream>>>(V1, counts, list_bk, list_w, Hsum, Ybuf);
    reduce_out<<<dim3(NB), 256, 0, stream>>>(Ybuf, out);
}